// Round 2
// baseline (145.592 us; speedup 1.0000x reference)
//
#include <hip/hip_runtime.h>
#include <stdint.h>

#define NT 2048
#define DT 128

typedef __bf16 bf16x8 __attribute__((ext_vector_type(8)));
typedef __bf16 bf16x4 __attribute__((ext_vector_type(4)));
typedef float  f32x16 __attribute__((ext_vector_type(16)));
typedef uint32_t u32x4 __attribute__((ext_vector_type(4)));

static __device__ __forceinline__ uint32_t pk2(float lo, float hi) {
    union { __bf16 h[2]; uint32_t u; } un;
    un.h[0] = (__bf16)lo; un.h[1] = (__bf16)hi;
    return un.u;
}

// ============================================================================
// prep: one-shot dtype/layout conversion.
//   blocks 0..511    : Qt[b][n][d] = bf16(Q[b][d][n])   (64x64 LDS transpose)
//   blocks 512..1023 : Kt[b][m][d] = bf16(K[b][d][m])
//   blocks 1024..2047: Vb[b][v][n] = bf16(V[b][v][n])   (straight convert)
// ============================================================================
__global__ __launch_bounds__(256)
void prep(const float* __restrict__ Q, const float* __restrict__ K,
          const float* __restrict__ V,
          __bf16* __restrict__ Qt, __bf16* __restrict__ Kt, __bf16* __restrict__ Vb)
{
    const int bid = blockIdx.x;
    const int t   = threadIdx.x;
    if (bid < 1024) {
        __shared__ float ls[64][65];            // +1 pad: conflict-free transpose
        const float* src = (bid < 512) ? Q : K;
        __bf16*      dst = (bid < 512) ? Qt : Kt;
        const int idx = bid & 511;
        const int b   = idx >> 6;               // 0..7
        const int di  = (idx >> 5) & 1;         // d-tile 0..1
        const int ni  = idx & 31;               // n-tile 0..31
        const int d0 = di * 64, n0 = ni * 64;
        const float* sb = src + (size_t)b * DT * NT;
        #pragma unroll
        for (int rr = 0; rr < 4; ++rr) {
            const int dl = (t >> 4) + 16 * rr;
            const float4 v4 = *(const float4*)(sb + (size_t)(d0 + dl) * NT + n0 + 4 * (t & 15));
            ls[dl][4 * (t & 15) + 0] = v4.x;
            ls[dl][4 * (t & 15) + 1] = v4.y;
            ls[dl][4 * (t & 15) + 2] = v4.z;
            ls[dl][4 * (t & 15) + 3] = v4.w;
        }
        __syncthreads();
        __bf16* db = dst + (size_t)b * NT * DT;
        #pragma unroll
        for (int rr = 0; rr < 4; ++rr) {
            const int nl = (t >> 4) + 16 * rr;
            bf16x4 pk;
            #pragma unroll
            for (int j = 0; j < 4; ++j) pk[j] = (__bf16)ls[4 * (t & 15) + j][nl];
            *(bf16x4*)(db + (size_t)(n0 + nl) * DT + d0 + 4 * (t & 15)) = pk;
        }
    } else {
        const int vb = bid - 1024;
        const size_t base = (size_t)vb * 2048 + (size_t)t * 8;
        const float4 a = *(const float4*)(V + base);
        const float4 c = *(const float4*)(V + base + 4);
        bf16x8 pk;
        pk[0] = (__bf16)a.x; pk[1] = (__bf16)a.y; pk[2] = (__bf16)a.z; pk[3] = (__bf16)a.w;
        pk[4] = (__bf16)c.x; pk[5] = (__bf16)c.y; pk[6] = (__bf16)c.z; pk[7] = (__bf16)c.w;
        *(bf16x8*)(Vb + base) = pk;
    }
}

// ============================================================================
// sig_attn3: ZERO LDS, ZERO barriers. 4 waves/block, wave w owns m-column 32w.
// Per 32-n chunk: GEMM1 (8 MFMA, Q-frags direct from global Qt) -> sigmoid in
// regs -> C-layout->B-layout via 4x shfl_xor(32) -> GEMM2 (8 MFMA over 4
// v-tiles, V-frags direct from global Vb). S never leaves the wave.
//   mfma_f32_32x32x16_bf16:
//     A: lane holds A[row=lane&31][k=(lane>>5)*8+j]
//     B: lane holds B[k=(lane>>5)*8+j][col=lane&31]
//     C/D: col=lane&31, row=(reg&3)+8*(reg>>2)+4*(lane>>5)
// Exchange derivation: lane (lq=0) holds S rows n={0-3,8-11,16-19,24-27},
// partner lane+32 holds n+4. B-frag kk needs n=16kk+8lq+j. Packing pairs
// a=pk2(p0,p1) b=pk2(p2,p3) c=pk2(p4,p5) d=pk2(p6,p7): send x0=lq?a:c,
// x1=lq?b:d through shfl_xor(32); frag words = {lq?y0:a, lq?y1:b, lq?c:y0,
// lq?d:y1}. Same for kk=1 with p8..p15.
// ============================================================================
__global__ __launch_bounds__(256, 2)
void sig_attn3(const __bf16* __restrict__ Qt, const __bf16* __restrict__ Kt,
               const __bf16* __restrict__ Vb, float* __restrict__ wsp)
{
    const int t   = threadIdx.x;
    const int w   = t >> 6;       // wave 0..3 -> m-column
    const int l   = t & 63;
    const int lq  = l >> 5;
    const int l31 = l & 31;

    const int bid   = blockIdx.x;
    const int b     = bid & 7;           // XCD-pinned batch
    const int mt    = (bid >> 3) & 15;
    const int ns    = bid >> 7;          // 0..3
    const int m_blk = mt * 128;
    const int n_base = ns * 512;

    const __bf16* Qtb = Qt + (size_t)b * NT * DT;
    const __bf16* Ktb = Kt + (size_t)b * NT * DT;
    const __bf16* Vbb = Vb + (size_t)b * DT * NT;

    const int mrow = 32 * w + l31;       // local m within 128-tile

    // ---- K -> register B-fragments: kf[k][j] = K[d=16k+8lq+j][m_blk+mrow]
    bf16x8 kf[8];
    #pragma unroll
    for (int k = 0; k < 8; ++k)
        kf[k] = *(const bf16x8*)(Ktb + (size_t)(m_blk + mrow) * DT + 16 * k + 8 * lq);

    f32x16 oacc[4];
    #pragma unroll
    for (int tv = 0; tv < 4; ++tv)
        #pragma unroll
        for (int r = 0; r < 16; ++r) oacc[tv][r] = 0.0f;

    // ---- Q A-frags chunk 0: qf[k][j] = Q[n0+l31][d=16k+8lq+j]
    bf16x8 qf[8];
    {
        const __bf16* q0 = Qtb + (size_t)(n_base + l31) * DT + 8 * lq;
        #pragma unroll
        for (int k = 0; k < 8; ++k) qf[k] = *(const bf16x8*)(q0 + 16 * k);
    }

    #pragma unroll 1
    for (int it = 0; it < 16; ++it) {
        const int n0 = n_base + it * 32;

        // ---- GEMM1: S[32n][32m] for this wave's m-column, K=128 d
        f32x16 s;
        #pragma unroll
        for (int r = 0; r < 16; ++r) s[r] = 0.0f;
        #pragma unroll
        for (int k = 0; k < 8; ++k)
            s = __builtin_amdgcn_mfma_f32_32x32x16_bf16(qf[k], kf[k], s, 0, 0, 0);

        // ---- reload qf for next chunk (regs dead; latency hides under rest)
        if (it < 15) {
            const __bf16* qn = Qtb + (size_t)(n0 + 32 + l31) * DT + 8 * lq;
            #pragma unroll
            for (int k = 0; k < 8; ++k) qf[k] = *(const bf16x8*)(qn + 16 * k);
        }

        // ---- sigmoid(x/sqrt(128)) in regs
        float p[16];
        #pragma unroll
        for (int r = 0; r < 16; ++r) {
            const float e = __expf(s[r] * -0.08838834764831845f);
            p[r] = __builtin_amdgcn_rcpf(1.0f + e);
        }

        // ---- pack to bf16 pairs + half-wave exchange -> B-frags bs0 (n0..15), bs1 (n16..31)
        const uint32_t a0 = pk2(p[0],  p[1]),  b0 = pk2(p[2],  p[3]);
        const uint32_t c0 = pk2(p[4],  p[5]),  d0 = pk2(p[6],  p[7]);
        const uint32_t a1 = pk2(p[8],  p[9]),  b1 = pk2(p[10], p[11]);
        const uint32_t c1 = pk2(p[12], p[13]), d1 = pk2(p[14], p[15]);

        const uint32_t y0 = __shfl_xor(lq ? a0 : c0, 32);
        const uint32_t y1 = __shfl_xor(lq ? b0 : d0, 32);
        const uint32_t y2 = __shfl_xor(lq ? a1 : c1, 32);
        const uint32_t y3 = __shfl_xor(lq ? b1 : d1, 32);

        u32x4 f0, f1;
        f0[0] = lq ? y0 : a0;  f0[1] = lq ? y1 : b0;
        f0[2] = lq ? c0 : y0;  f0[3] = lq ? d0 : y1;
        f1[0] = lq ? y2 : a1;  f1[1] = lq ? y3 : b1;
        f1[2] = lq ? c1 : y2;  f1[3] = lq ? d1 : y3;
        const bf16x8 bs0 = __builtin_bit_cast(bf16x8, f0);
        const bf16x8 bs1 = __builtin_bit_cast(bf16x8, f1);

        // ---- GEMM2: oacc[tv] += V[32tv+..][n0..n0+31] * S ; V direct from global
        #pragma unroll
        for (int tv = 0; tv < 4; ++tv) {
            const __bf16* vp = Vbb + (size_t)(32 * tv + l31) * NT + n0 + 8 * lq;
            const bf16x8 av0 = *(const bf16x8*)(vp);
            const bf16x8 av1 = *(const bf16x8*)(vp + 16);
            oacc[tv] = __builtin_amdgcn_mfma_f32_32x32x16_bf16(av0, bs0, oacc[tv], 0, 0, 0);
            oacc[tv] = __builtin_amdgcn_mfma_f32_32x32x16_bf16(av1, bs1, oacc[tv], 0, 0, 0);
        }
    }

    // ---- epilogue: per-block partial [v 128][m 128] (same layout as before)
    float* wsb = wsp + (size_t)bid * 16384;
    #pragma unroll
    for (int tv = 0; tv < 4; ++tv) {
        #pragma unroll
        for (int r = 0; r < 16; ++r) {
            const int v = 32 * tv + (r & 3) + 8 * (r >> 2) + 4 * lq;
            wsb[v * 128 + mrow] = oacc[tv][r];
        }
    }
}

// ============================================================================
// v1 kernel kept verbatim as fallback for small-ws harnesses
// ============================================================================
template <int WSMODE>
__global__ __launch_bounds__(512, 4)
void sig_attn(const float* __restrict__ Q, const float* __restrict__ K,
              const float* __restrict__ V, float* __restrict__ outp)
{
    __shared__ __align__(16) __bf16 Qs[64 * 128];
    __shared__ __align__(16) __bf16 Ss[128 * 64];
    __shared__ __align__(16) __bf16 Vs[2][128 * 64];

    const int t   = threadIdx.x;
    const int w   = t >> 6;
    const int l   = t & 63;
    const int lq  = l >> 5;
    const int l31 = l & 31;
    const int wm  = w & 3;
    const int wn  = w >> 2;

    const int bid    = blockIdx.x;
    const int b      = bid & 7;
    const int mt     = (bid >> 3) & 15;
    const int ns     = bid >> 7;
    const int m_blk  = mt * 128;
    const int n_base = ns * 512;

    const float* Qb = Q + (size_t)b * DT * NT;
    const float* Kb = K + (size_t)b * DT * NT;
    const float* Vb = V + (size_t)b * DT * NT;

    const int mrow = 32 * wm + l31;

    bf16x8 kf[8];
    #pragma unroll
    for (int half = 0; half < 2; ++half) {
        float tmp[4][8];
        #pragma unroll
        for (int k2 = 0; k2 < 4; ++k2)
            #pragma unroll
            for (int j = 0; j < 8; ++j)
                tmp[k2][j] = Kb[(size_t)((half * 4 + k2) * 16 + lq * 8 + j) * NT + m_blk + mrow];
        #pragma unroll
        for (int k2 = 0; k2 < 4; ++k2) {
            bf16x8 f;
            #pragma unroll
            for (int j = 0; j < 8; ++j) f[j] = (__bf16)tmp[k2][j];
            kf[half * 4 + k2] = f;
        }
    }

    f32x16 oacc[2];
    #pragma unroll
    for (int tv = 0; tv < 2; ++tv)
        #pragma unroll
        for (int r = 0; r < 16; ++r)
            oacc[tv][r] = 0.0f;

    float qp[16];
    #pragma unroll
    for (int r = 0; r < 2; ++r)
        #pragma unroll
        for (int j = 0; j < 8; ++j)
            qp[r * 8 + j] = Qb[(size_t)(64 * r + 8 * w + j) * NT + n_base + l];
    float4 vp[4];
    #pragma unroll
    for (int p = 0; p < 4; ++p)
        vp[p] = *(const float4*)(Vb + (size_t)(p * 32 + (t >> 4)) * NT + n_base + 4 * (t & 15));

    for (int it = 0; it < 8; ++it) {
        __bf16* Vbuf = Vs[it & 1];

        #pragma unroll
        for (int r = 0; r < 2; ++r) {
            bf16x8 pk;
            #pragma unroll
            for (int j = 0; j < 8; ++j) pk[j] = (__bf16)qp[r * 8 + j];
            *(bf16x8*)&Qs[l * 128 + ((8 * r + w) ^ (l & 15)) * 8] = pk;
        }
        #pragma unroll
        for (int p = 0; p < 4; ++p) {
            const int v  = p * 32 + (t >> 4);
            const int ng = t & 15;
            bf16x4 pk;
            pk[0] = (__bf16)vp[p].x;
            pk[1] = (__bf16)vp[p].y;
            pk[2] = (__bf16)vp[p].z;
            pk[3] = (__bf16)vp[p].w;
            *(bf16x4*)&Vbuf[v * 64 + ((ng >> 1) ^ (v & 7)) * 8 + 4 * (ng & 1)] = pk;
        }
        __syncthreads();

        const int n0n = n_base + ((it + 1) & 7) * 64;
        #pragma unroll
        for (int r = 0; r < 2; ++r)
            #pragma unroll
            for (int j = 0; j < 8; ++j)
                qp[r * 8 + j] = Qb[(size_t)(64 * r + 8 * w + j) * NT + n0n + l];
        #pragma unroll
        for (int p = 0; p < 4; ++p)
            vp[p] = *(const float4*)(Vb + (size_t)(p * 32 + (t >> 4)) * NT + n0n + 4 * (t & 15));

        f32x16 sacc;
        #pragma unroll
        for (int r = 0; r < 16; ++r) sacc[r] = 0.0f;
        const int nrow = 32 * wn + l31;
        #pragma unroll
        for (int k = 0; k < 8; ++k) {
            const bf16x8 af =
                *(const bf16x8*)&Qs[nrow * 128 + ((2 * k + lq) ^ (nrow & 15)) * 8];
            sacc = __builtin_amdgcn_mfma_f32_32x32x16_bf16(af, kf[k], sacc, 0, 0, 0);
        }

        #pragma unroll
        for (int g = 0; g < 4; ++g) {
            bf16x4 pk;
            #pragma unroll
            for (int rr = 0; rr < 4; ++rr) {
                const float x = sacc[4 * g + rr];
                const float e = __expf(x * -0.08838834764831845f);
                pk[rr] = (__bf16)__builtin_amdgcn_rcpf(1.0f + e);
            }
            *(bf16x4*)&Ss[mrow * 64 + ((4 * wn + g) ^ (mrow & 7)) * 8 + 4 * lq] = pk;
        }
        __syncthreads();

        #pragma unroll
        for (int k = 0; k < 4; ++k) {
            const int sw = 2 * k + lq;
            const bf16x8 av0 =
                *(const bf16x8*)&Vbuf[(64 * wn + l31) * 64 + (sw ^ (l31 & 7)) * 8];
            const bf16x8 av1 =
                *(const bf16x8*)&Vbuf[(64 * wn + 32 + l31) * 64 + (sw ^ (l31 & 7)) * 8];
            const bf16x8 bs =
                *(const bf16x8*)&Ss[mrow * 64 + (sw ^ (mrow & 7)) * 8];
            oacc[0] = __builtin_amdgcn_mfma_f32_32x32x16_bf16(av0, bs, oacc[0], 0, 0, 0);
            oacc[1] = __builtin_amdgcn_mfma_f32_32x32x16_bf16(av1, bs, oacc[1], 0, 0, 0);
        }
    }

    if (WSMODE == 0) {
        float* wsb = outp + (size_t)bid * 16384;
        #pragma unroll
        for (int tv = 0; tv < 2; ++tv) {
            #pragma unroll
            for (int r = 0; r < 16; ++r) {
                const int v = 64 * wn + 32 * tv + (r & 3) + 8 * (r >> 2) + 4 * lq;
                wsb[v * 128 + mrow] = oacc[tv][r];
            }
        }
    } else {
        float* Ob = outp + (size_t)b * DT * NT;
        #pragma unroll
        for (int tv = 0; tv < 2; ++tv) {
            #pragma unroll
            for (int r = 0; r < 16; ++r) {
                const int v = 64 * wn + 32 * tv + (r & 3) + 8 * (r >> 2) + 4 * lq;
                atomicAdd(&Ob[(size_t)v * NT + m_blk + mrow], oacc[tv][r]);
            }
        }
    }
}

// out[o] = sum over 4 n-splits of ws partials; float4 per thread, fully coalesced
__global__ __launch_bounds__(256)
void reduce4(const float4* __restrict__ ws, float4* __restrict__ out)
{
    const int i = blockIdx.x * 256 + threadIdx.x;
    const int o = i * 4;
    const int m_glob = o & 2047;
    const int vb     = o >> 11;
    const int v      = vb & 127;
    const int bb     = vb >> 7;
    const int mt     = m_glob >> 7;
    const int m      = m_glob & 127;
    const size_t base = ((size_t)(bb + 8 * mt) * 16384 + (size_t)v * 128 + m) >> 2;
    const size_t strd = 524288;
    float4 a = ws[base];
    float4 c = ws[base + strd];
    float4 d = ws[base + 2 * strd];
    float4 e = ws[base + 3 * strd];
    float4 r;
    r.x = a.x + c.x + d.x + e.x;
    r.y = a.y + c.y + d.y + e.y;
    r.z = a.z + c.z + d.z + e.z;
    r.w = a.w + c.w + d.w + e.w;
    out[i] = r;
}

extern "C" void kernel_launch(void* const* d_in, const int* in_sizes, int n_in,
                              void* d_out, int out_size, void* d_ws, size_t ws_size,
                              hipStream_t stream) {
    (void)in_sizes; (void)n_in;
    const float* Q = (const float*)d_in[0];
    const float* K = (const float*)d_in[1];
    const float* V = (const float*)d_in[2];
    const size_t PART  = (size_t)512 * 16384 * 4;          // 33.5 MB fp32 partials
    const size_t CONV  = (size_t)3 * 8 * NT * DT * 2;      // 12.6 MB bf16 Qt/Kt/Vb
    if (ws_size >= PART + CONV) {
        __bf16* Qt = (__bf16*)((char*)d_ws + PART);
        __bf16* Kt = Qt + (size_t)8 * NT * DT;
        __bf16* Vb = Kt + (size_t)8 * NT * DT;
        prep<<<dim3(2048), dim3(256), 0, stream>>>(Q, K, V, Qt, Kt, Vb);
        sig_attn3<<<dim3(512), dim3(256), 0, stream>>>(Qt, Kt, Vb, (float*)d_ws);
        reduce4<<<dim3(2048), dim3(256), 0, stream>>>((const float4*)d_ws, (float4*)d_out);
    } else if (ws_size >= PART) {
        sig_attn<0><<<dim3(512), dim3(512), 0, stream>>>(Q, K, V, (float*)d_ws);
        reduce4<<<dim3(2048), dim3(256), 0, stream>>>((const float4*)d_ws, (float4*)d_out);
    } else {
        hipMemsetAsync(d_out, 0, (size_t)out_size * sizeof(float), stream);
        sig_attn<1><<<dim3(512), dim3(512), 0, stream>>>(Q, K, V, (float*)d_out);
    }
}

// Round 3
// 120.861 us; speedup vs baseline: 1.2046x; 1.2046x over previous
//
#include <hip/hip_runtime.h>
#include <stdint.h>

#define NT 2048
#define DT 128

typedef __bf16 bf16x8 __attribute__((ext_vector_type(8)));
typedef __bf16 bf16x4 __attribute__((ext_vector_type(4)));
typedef float  f32x16 __attribute__((ext_vector_type(16)));
typedef uint32_t u32x4 __attribute__((ext_vector_type(4)));

static __device__ __forceinline__ uint32_t pk2(float lo, float hi) {
    union { __bf16 h[2]; uint32_t u; } un;
    un.h[0] = (__bf16)lo; un.h[1] = (__bf16)hi;
    return un.u;
}

// ============================================================================
// prep2: convert Q,K,V fp32 into MFMA-FRAGMENT-ORDER bf16 buffers so every
// fragment load in the main kernel is one coalesced 1KB wave-load.
//   Qf[b][c][k][l][j] = Q[b][d=16k+8*(l>>5)+j][n=32c+(l&31)]     (4 MB)
//   Kf[b][mc][k][l][j] = K[b][d=16k+8*(l>>5)+j][m=32mc+(l&31)]   (4 MB)
//   Vf[b][c][vc][kk][l][j] = V[b][v=32vc+(l&31)][n=32c+16kk+8*(l>>5)+j] (4 MB)
// blocks 0..511: Q/K (LDS transpose of a [128d][64n] tile); 512..767: V.
// ============================================================================
__global__ __launch_bounds__(256)
void prep2(const float* __restrict__ Q, const float* __restrict__ K,
           const float* __restrict__ V,
           __bf16* __restrict__ Qf, __bf16* __restrict__ Kf, __bf16* __restrict__ Vf)
{
    const int bid = blockIdx.x;
    const int t   = threadIdx.x;
    if (bid < 512) {
        __shared__ float ls[128][65];
        const int which = bid >> 8;            // 0=Q, 1=K
        const float* src = which ? K : Q;
        __bf16*      dst = which ? Kf : Qf;
        const int idx = bid & 255;
        const int b   = idx >> 5;              // 0..7
        const int ct  = idx & 31;              // 64-wide n/m tile
        const int n0  = ct * 64;
        const float* sb = src + (size_t)b * DT * NT;
        // load [128 d][64 n] tile, coalesced float4 along n
        #pragma unroll
        for (int rr = 0; rr < 8; ++rr) {
            const int d = (t >> 4) + 16 * rr;
            const float4 v4 = *(const float4*)(sb + (size_t)d * NT + n0 + 4 * (t & 15));
            ls[d][4 * (t & 15) + 0] = v4.x;
            ls[d][4 * (t & 15) + 1] = v4.y;
            ls[d][4 * (t & 15) + 2] = v4.z;
            ls[d][4 * (t & 15) + 3] = v4.w;
        }
        __syncthreads();
        // gather fragments and write coalesced
        const int l  = t & 63;
        const int kq = t >> 6;                 // 0..3
        const int lq = l >> 5, l31 = l & 31;
        #pragma unroll
        for (int c = 0; c < 2; ++c) {
            #pragma unroll
            for (int kh = 0; kh < 2; ++kh) {
                const int k = kq + 4 * kh;
                bf16x8 f;
                #pragma unroll
                for (int j = 0; j < 8; ++j)
                    f[j] = (__bf16)ls[16 * k + 8 * lq + j][32 * c + l31];
                *(bf16x8*)(dst + ((size_t)((b * 64 + 2 * ct + c) * 8 + k)) * 512 + l * 8) = f;
            }
        }
    } else {
        const int idx = bid - 512;             // 0..255
        const int b   = idx >> 5;
        const int cg  = idx & 31;
        const int l   = t & 63;
        const int vc  = t >> 6;                // 0..3
        const int lq  = l >> 5, l31 = l & 31;
        const float* vsrc = V + (size_t)b * DT * NT;
        #pragma unroll
        for (int ci = 0; ci < 2; ++ci) {
            const int c = 2 * cg + ci;
            #pragma unroll
            for (int kk = 0; kk < 2; ++kk) {
                const float* p = vsrc + (size_t)(32 * vc + l31) * NT + 32 * c + 16 * kk + 8 * lq;
                const float4 x = *(const float4*)p;
                const float4 y = *(const float4*)(p + 4);
                bf16x8 f;
                f[0] = (__bf16)x.x; f[1] = (__bf16)x.y; f[2] = (__bf16)x.z; f[3] = (__bf16)x.w;
                f[4] = (__bf16)y.x; f[5] = (__bf16)y.y; f[6] = (__bf16)y.z; f[7] = (__bf16)y.w;
                *(bf16x8*)(Vf + ((size_t)((b * 64 + c) * 4 + vc) * 2 + kk) * 512 + l * 8) = f;
            }
        }
    }
}

// ============================================================================
// sig_attn4: zero LDS, zero barriers, fully-coalesced fragment streams.
// Grid 1024: bid = b + 8*mt + 128*ns + 512*vh. 4 waves/block; wave w owns
// m-column 4*mt+w. Per 32-n chunk: GEMM1 (8 MFMA) -> sigmoid in regs ->
// C->B layout swap via 4x shfl_xor(32) (verified in attn3) -> GEMM2 for this
// block's v-half (2 v-tiles, 4 MFMA). GEMM1 is duplicated across the 2
// v-half blocks (1.5x MFMA) to buy occupancy: 4 blocks/CU = 4 waves/SIMD.
//   mfma_f32_32x32x16_bf16 C/D: col=lane&31, row=(reg&3)+8*(reg>>2)+4*(lane>>5)
// ============================================================================
__global__ __launch_bounds__(256, 4)
void sig_attn4(const __bf16* __restrict__ Qf, const __bf16* __restrict__ Kf,
               const __bf16* __restrict__ Vf, float* __restrict__ wsp)
{
    const int t   = threadIdx.x;
    const int w   = t >> 6;
    const int l   = t & 63;
    const int lq  = l >> 5;
    const int l31 = l & 31;

    const int bid = blockIdx.x;
    const int b   = bid & 7;
    const int mt  = (bid >> 3) & 15;
    const int ns  = (bid >> 7) & 3;
    const int vh  = bid >> 9;              // 0..1

    const int mrow = 32 * w + l31;         // local m within 128-tile

    // ---- K B-frags for this wave's m-column (coalesced 1KB loads)
    const __bf16* kfp = Kf + ((size_t)((b * 64 + 4 * mt + w) * 8)) * 512 + l * 8;
    bf16x8 kf[8];
    #pragma unroll
    for (int k = 0; k < 8; ++k) kf[k] = *(const bf16x8*)(kfp + (size_t)k * 512);

    f32x16 oacc[2];
    #pragma unroll
    for (int tv = 0; tv < 2; ++tv)
        #pragma unroll
        for (int r = 0; r < 16; ++r) oacc[tv][r] = 0.0f;

    // ---- Q A-frags chunk 0
    const int c_base = ns * 16;
    const __bf16* qbase = Qf + ((size_t)(b * 64 + c_base) * 8) * 512 + l * 8;
    bf16x8 qf[8];
    #pragma unroll
    for (int k = 0; k < 8; ++k) qf[k] = *(const bf16x8*)(qbase + (size_t)k * 512);

    const __bf16* vbase = Vf + ((size_t)((b * 64 + c_base) * 4 + 2 * vh) * 2) * 512 + l * 8;

    #pragma unroll 1
    for (int it = 0; it < 16; ++it) {
        // ---- GEMM1: S[32n][32m], K=128 d
        f32x16 s;
        #pragma unroll
        for (int r = 0; r < 16; ++r) s[r] = 0.0f;
        #pragma unroll
        for (int k = 0; k < 8; ++k)
            s = __builtin_amdgcn_mfma_f32_32x32x16_bf16(qf[k], kf[k], s, 0, 0, 0);

        // ---- V frags for this chunk (issued early; consumed after exchange)
        const __bf16* vp = vbase + (size_t)it * 8 * 512;
        const bf16x8 av0 = *(const bf16x8*)(vp);                    // vc=2vh,   kk=0
        const bf16x8 av1 = *(const bf16x8*)(vp + 512);              // vc=2vh,   kk=1
        const bf16x8 av2 = *(const bf16x8*)(vp + 1024);             // vc=2vh+1, kk=0
        const bf16x8 av3 = *(const bf16x8*)(vp + 1536);             // vc=2vh+1, kk=1

        // ---- prefetch next chunk's Q frags (qf dead after GEMM1)
        if (it < 15) {
            const __bf16* qn = qbase + (size_t)(it + 1) * 8 * 512;
            #pragma unroll
            for (int k = 0; k < 8; ++k) qf[k] = *(const bf16x8*)(qn + (size_t)k * 512);
        }

        // ---- sigmoid(x/sqrt(128)) in regs
        float p[16];
        #pragma unroll
        for (int r = 0; r < 16; ++r) {
            const float e = __expf(s[r] * -0.08838834764831845f);
            p[r] = __builtin_amdgcn_rcpf(1.0f + e);
        }

        // ---- pack + half-wave exchange -> B-frags bs0 (n0..15), bs1 (n16..31)
        const uint32_t a0 = pk2(p[0],  p[1]),  b0 = pk2(p[2],  p[3]);
        const uint32_t c0 = pk2(p[4],  p[5]),  d0 = pk2(p[6],  p[7]);
        const uint32_t a1 = pk2(p[8],  p[9]),  b1 = pk2(p[10], p[11]);
        const uint32_t c1 = pk2(p[12], p[13]), d1 = pk2(p[14], p[15]);

        const uint32_t y0 = __shfl_xor(lq ? a0 : c0, 32);
        const uint32_t y1 = __shfl_xor(lq ? b0 : d0, 32);
        const uint32_t y2 = __shfl_xor(lq ? a1 : c1, 32);
        const uint32_t y3 = __shfl_xor(lq ? b1 : d1, 32);

        u32x4 f0, f1;
        f0[0] = lq ? y0 : a0;  f0[1] = lq ? y1 : b0;
        f0[2] = lq ? c0 : y0;  f0[3] = lq ? d0 : y1;
        f1[0] = lq ? y2 : a1;  f1[1] = lq ? y3 : b1;
        f1[2] = lq ? c1 : y2;  f1[3] = lq ? d1 : y3;
        const bf16x8 bs0 = __builtin_bit_cast(bf16x8, f0);
        const bf16x8 bs1 = __builtin_bit_cast(bf16x8, f1);

        // ---- GEMM2: this block's v-half only
        oacc[0] = __builtin_amdgcn_mfma_f32_32x32x16_bf16(av0, bs0, oacc[0], 0, 0, 0);
        oacc[0] = __builtin_amdgcn_mfma_f32_32x32x16_bf16(av1, bs1, oacc[0], 0, 0, 0);
        oacc[1] = __builtin_amdgcn_mfma_f32_32x32x16_bf16(av2, bs0, oacc[1], 0, 0, 0);
        oacc[1] = __builtin_amdgcn_mfma_f32_32x32x16_bf16(av3, bs1, oacc[1], 0, 0, 0);
    }

    // ---- epilogue: per-block partial [vloc 64][m 128]
    float* wsb = wsp + (size_t)bid * 8192;
    #pragma unroll
    for (int tv = 0; tv < 2; ++tv) {
        #pragma unroll
        for (int r = 0; r < 16; ++r) {
            const int vloc = 32 * tv + (r & 3) + 8 * (r >> 2) + 4 * lq;
            wsb[vloc * 128 + mrow] = oacc[tv][r];
        }
    }
}

// sum the 4 n-split partials of the 1024-block layout
__global__ __launch_bounds__(256)
void reduce4b(const float4* __restrict__ ws, float4* __restrict__ out)
{
    const int i = blockIdx.x * 256 + threadIdx.x;    // float4 index, 0..524287
    const int o = i * 4;
    const int m_glob = o & 2047;
    const int vb     = o >> 11;        // v + 128*b
    const int v      = vb & 127;
    const int bb     = vb >> 7;
    const int mt     = m_glob >> 7;
    const int m      = m_glob & 127;
    const int vh     = v >> 6;
    const int vloc   = v & 63;
    const size_t base = ((size_t)(bb + 8 * mt + 512 * vh) * 8192 + (size_t)vloc * 128 + m) >> 2;
    const size_t strd = 262144;        // 128 blocks * 8192 floats / 4
    float4 a = ws[base];
    float4 c = ws[base + strd];
    float4 d = ws[base + 2 * strd];
    float4 e = ws[base + 3 * strd];
    float4 r;
    r.x = a.x + c.x + d.x + e.x;
    r.y = a.y + c.y + d.y + e.y;
    r.z = a.z + c.z + d.z + e.z;
    r.w = a.w + c.w + d.w + e.w;
    out[i] = r;
}

// ============================================================================
// v1 kernel + reduce4 kept verbatim as fallback for small-ws harnesses
// ============================================================================
template <int WSMODE>
__global__ __launch_bounds__(512, 4)
void sig_attn(const float* __restrict__ Q, const float* __restrict__ K,
              const float* __restrict__ V, float* __restrict__ outp)
{
    __shared__ __align__(16) __bf16 Qs[64 * 128];
    __shared__ __align__(16) __bf16 Ss[128 * 64];
    __shared__ __align__(16) __bf16 Vs[2][128 * 64];

    const int t   = threadIdx.x;
    const int w   = t >> 6;
    const int l   = t & 63;
    const int lq  = l >> 5;
    const int l31 = l & 31;
    const int wm  = w & 3;
    const int wn  = w >> 2;

    const int bid    = blockIdx.x;
    const int b      = bid & 7;
    const int mt     = (bid >> 3) & 15;
    const int ns     = bid >> 7;
    const int m_blk  = mt * 128;
    const int n_base = ns * 512;

    const float* Qb = Q + (size_t)b * DT * NT;
    const float* Kb = K + (size_t)b * DT * NT;
    const float* Vb = V + (size_t)b * DT * NT;

    const int mrow = 32 * wm + l31;

    bf16x8 kf[8];
    #pragma unroll
    for (int half = 0; half < 2; ++half) {
        float tmp[4][8];
        #pragma unroll
        for (int k2 = 0; k2 < 4; ++k2)
            #pragma unroll
            for (int j = 0; j < 8; ++j)
                tmp[k2][j] = Kb[(size_t)((half * 4 + k2) * 16 + lq * 8 + j) * NT + m_blk + mrow];
        #pragma unroll
        for (int k2 = 0; k2 < 4; ++k2) {
            bf16x8 f;
            #pragma unroll
            for (int j = 0; j < 8; ++j) f[j] = (__bf16)tmp[k2][j];
            kf[half * 4 + k2] = f;
        }
    }

    f32x16 oacc[2];
    #pragma unroll
    for (int tv = 0; tv < 2; ++tv)
        #pragma unroll
        for (int r = 0; r < 16; ++r)
            oacc[tv][r] = 0.0f;

    float qp[16];
    #pragma unroll
    for (int r = 0; r < 2; ++r)
        #pragma unroll
        for (int j = 0; j < 8; ++j)
            qp[r * 8 + j] = Qb[(size_t)(64 * r + 8 * w + j) * NT + n_base + l];
    float4 vp[4];
    #pragma unroll
    for (int p = 0; p < 4; ++p)
        vp[p] = *(const float4*)(Vb + (size_t)(p * 32 + (t >> 4)) * NT + n_base + 4 * (t & 15));

    for (int it = 0; it < 8; ++it) {
        __bf16* Vbuf = Vs[it & 1];

        #pragma unroll
        for (int r = 0; r < 2; ++r) {
            bf16x8 pk;
            #pragma unroll
            for (int j = 0; j < 8; ++j) pk[j] = (__bf16)qp[r * 8 + j];
            *(bf16x8*)&Qs[l * 128 + ((8 * r + w) ^ (l & 15)) * 8] = pk;
        }
        #pragma unroll
        for (int p = 0; p < 4; ++p) {
            const int v  = p * 32 + (t >> 4);
            const int ng = t & 15;
            bf16x4 pk;
            pk[0] = (__bf16)vp[p].x;
            pk[1] = (__bf16)vp[p].y;
            pk[2] = (__bf16)vp[p].z;
            pk[3] = (__bf16)vp[p].w;
            *(bf16x4*)&Vbuf[v * 64 + ((ng >> 1) ^ (v & 7)) * 8 + 4 * (ng & 1)] = pk;
        }
        __syncthreads();

        const int n0n = n_base + ((it + 1) & 7) * 64;
        #pragma unroll
        for (int r = 0; r < 2; ++r)
            #pragma unroll
            for (int j = 0; j < 8; ++j)
                qp[r * 8 + j] = Qb[(size_t)(64 * r + 8 * w + j) * NT + n0n + l];
        #pragma unroll
        for (int p = 0; p < 4; ++p)
            vp[p] = *(const float4*)(Vb + (size_t)(p * 32 + (t >> 4)) * NT + n0n + 4 * (t & 15));

        f32x16 sacc;
        #pragma unroll
        for (int r = 0; r < 16; ++r) sacc[r] = 0.0f;
        const int nrow = 32 * wn + l31;
        #pragma unroll
        for (int k = 0; k < 8; ++k) {
            const bf16x8 af =
                *(const bf16x8*)&Qs[nrow * 128 + ((2 * k + lq) ^ (nrow & 15)) * 8];
            sacc = __builtin_amdgcn_mfma_f32_32x32x16_bf16(af, kf[k], sacc, 0, 0, 0);
        }

        #pragma unroll
        for (int g = 0; g < 4; ++g) {
            bf16x4 pk;
            #pragma unroll
            for (int rr = 0; rr < 4; ++rr) {
                const float x = sacc[4 * g + rr];
                const float e = __expf(x * -0.08838834764831845f);
                pk[rr] = (__bf16)__builtin_amdgcn_rcpf(1.0f + e);
            }
            *(bf16x4*)&Ss[mrow * 64 + ((4 * wn + g) ^ (mrow & 7)) * 8 + 4 * lq] = pk;
        }
        __syncthreads();

        #pragma unroll
        for (int k = 0; k < 4; ++k) {
            const int sw = 2 * k + lq;
            const bf16x8 av0 =
                *(const bf16x8*)&Vbuf[(64 * wn + l31) * 64 + (sw ^ (l31 & 7)) * 8];
            const bf16x8 av1 =
                *(const bf16x8*)&Vbuf[(64 * wn + 32 + l31) * 64 + (sw ^ (l31 & 7)) * 8];
            const bf16x8 bs =
                *(const bf16x8*)&Ss[mrow * 64 + (sw ^ (mrow & 7)) * 8];
            oacc[0] = __builtin_amdgcn_mfma_f32_32x32x16_bf16(av0, bs, oacc[0], 0, 0, 0);
            oacc[1] = __builtin_amdgcn_mfma_f32_32x32x16_bf16(av1, bs, oacc[1], 0, 0, 0);
        }
    }

    if (WSMODE == 0) {
        float* wsb = outp + (size_t)bid * 16384;
        #pragma unroll
        for (int tv = 0; tv < 2; ++tv) {
            #pragma unroll
            for (int r = 0; r < 16; ++r) {
                const int v = 64 * wn + 32 * tv + (r & 3) + 8 * (r >> 2) + 4 * lq;
                wsb[v * 128 + mrow] = oacc[tv][r];
            }
        }
    } else {
        float* Ob = outp + (size_t)b * DT * NT;
        #pragma unroll
        for (int tv = 0; tv < 2; ++tv) {
            #pragma unroll
            for (int r = 0; r < 16; ++r) {
                const int v = 64 * wn + 32 * tv + (r & 3) + 8 * (r >> 2) + 4 * lq;
                atomicAdd(&Ob[(size_t)v * NT + m_blk + mrow], oacc[tv][r]);
            }
        }
    }
}

__global__ __launch_bounds__(256)
void reduce4(const float4* __restrict__ ws, float4* __restrict__ out)
{
    const int i = blockIdx.x * 256 + threadIdx.x;
    const int o = i * 4;
    const int m_glob = o & 2047;
    const int vb     = o >> 11;
    const int v      = vb & 127;
    const int bb     = vb >> 7;
    const int mt     = m_glob >> 7;
    const int m      = m_glob & 127;
    const size_t base = ((size_t)(bb + 8 * mt) * 16384 + (size_t)v * 128 + m) >> 2;
    const size_t strd = 524288;
    float4 a = ws[base];
    float4 c = ws[base + strd];
    float4 d = ws[base + 2 * strd];
    float4 e = ws[base + 3 * strd];
    float4 r;
    r.x = a.x + c.x + d.x + e.x;
    r.y = a.y + c.y + d.y + e.y;
    r.z = a.z + c.z + d.z + e.z;
    r.w = a.w + c.w + d.w + e.w;
    out[i] = r;
}

extern "C" void kernel_launch(void* const* d_in, const int* in_sizes, int n_in,
                              void* d_out, int out_size, void* d_ws, size_t ws_size,
                              hipStream_t stream) {
    (void)in_sizes; (void)n_in;
    const float* Q = (const float*)d_in[0];
    const float* K = (const float*)d_in[1];
    const float* V = (const float*)d_in[2];
    const size_t PART2 = (size_t)1024 * 8192 * 4;          // 33.5 MB fp32 partials
    const size_t FRAGB = (size_t)2097152 * 2;              // 4 MB per operand buffer
    const size_t PART  = (size_t)512 * 16384 * 4;          // old fallback partials
    if (ws_size >= PART2 + 3 * FRAGB) {                    // 46.1 MB (same as proven)
        __bf16* Qf = (__bf16*)((char*)d_ws + PART2);
        __bf16* Kf = Qf + 2097152;
        __bf16* Vf = Kf + 2097152;
        prep2<<<dim3(768), dim3(256), 0, stream>>>(Q, K, V, Qf, Kf, Vf);
        sig_attn4<<<dim3(1024), dim3(256), 0, stream>>>(Qf, Kf, Vf, (float*)d_ws);
        reduce4b<<<dim3(2048), dim3(256), 0, stream>>>((const float4*)d_ws, (float4*)d_out);
    } else if (ws_size >= PART) {
        sig_attn<0><<<dim3(512), dim3(512), 0, stream>>>(Q, K, V, (float*)d_ws);
        reduce4<<<dim3(2048), dim3(256), 0, stream>>>((const float4*)d_ws, (float4*)d_out);
    } else {
        hipMemsetAsync(d_out, 0, (size_t)out_size * sizeof(float), stream);
        sig_attn<1><<<dim3(512), dim3(512), 0, stream>>>(Q, K, V, (float*)d_out);
    }
}

// Round 4
// 110.932 us; speedup vs baseline: 1.3125x; 1.0895x over previous
//
#include <hip/hip_runtime.h>
#include <stdint.h>

#define NT 2048
#define DT 128

typedef __bf16 bf16x8 __attribute__((ext_vector_type(8)));
typedef __bf16 bf16x4 __attribute__((ext_vector_type(4)));
typedef float  f32x16 __attribute__((ext_vector_type(16)));
typedef uint32_t u32x4 __attribute__((ext_vector_type(4)));

static __device__ __forceinline__ uint32_t pk2(float lo, float hi) {
    union { __bf16 h[2]; uint32_t u; } un;
    un.h[0] = (__bf16)lo; un.h[1] = (__bf16)hi;
    return un.u;
}

// ============================================================================
// prep2: convert Q,K,V fp32 into MFMA-FRAGMENT-ORDER bf16 buffers so every
// fragment load in the main kernel is one coalesced 1KB wave-load.
//   Qf[b][c][k][l][j] = Q[b][d=16k+8*(l>>5)+j][n=32c+(l&31)]     (4 MB)
//   Kf[b][mc][k][l][j] = K[b][d=16k+8*(l>>5)+j][m=32mc+(l&31)]   (4 MB)
//   Vf[b][c][vc][kk][l][j] = V[b][v=32vc+(l&31)][n=32c+16kk+8*(l>>5)+j] (4 MB)
// blocks 0..511: Q/K (LDS transpose of a [128d][64n] tile); 512..767: V.
// ============================================================================
__global__ __launch_bounds__(256)
void prep2(const float* __restrict__ Q, const float* __restrict__ K,
           const float* __restrict__ V,
           __bf16* __restrict__ Qf, __bf16* __restrict__ Kf, __bf16* __restrict__ Vf)
{
    const int bid = blockIdx.x;
    const int t   = threadIdx.x;
    if (bid < 512) {
        __shared__ float ls[128][65];
        const int which = bid >> 8;            // 0=Q, 1=K
        const float* src = which ? K : Q;
        __bf16*      dst = which ? Kf : Qf;
        const int idx = bid & 255;
        const int b   = idx >> 5;              // 0..7
        const int ct  = idx & 31;              // 64-wide n/m tile
        const int n0  = ct * 64;
        const float* sb = src + (size_t)b * DT * NT;
        #pragma unroll
        for (int rr = 0; rr < 8; ++rr) {
            const int d = (t >> 4) + 16 * rr;
            const float4 v4 = *(const float4*)(sb + (size_t)d * NT + n0 + 4 * (t & 15));
            ls[d][4 * (t & 15) + 0] = v4.x;
            ls[d][4 * (t & 15) + 1] = v4.y;
            ls[d][4 * (t & 15) + 2] = v4.z;
            ls[d][4 * (t & 15) + 3] = v4.w;
        }
        __syncthreads();
        const int l  = t & 63;
        const int kq = t >> 6;                 // 0..3
        const int lq = l >> 5, l31 = l & 31;
        #pragma unroll
        for (int c = 0; c < 2; ++c) {
            #pragma unroll
            for (int kh = 0; kh < 2; ++kh) {
                const int k = kq + 4 * kh;
                bf16x8 f;
                #pragma unroll
                for (int j = 0; j < 8; ++j)
                    f[j] = (__bf16)ls[16 * k + 8 * lq + j][32 * c + l31];
                *(bf16x8*)(dst + ((size_t)((b * 64 + 2 * ct + c) * 8 + k)) * 512 + l * 8) = f;
            }
        }
    } else {
        const int idx = bid - 512;             // 0..255
        const int b   = idx >> 5;
        const int cg  = idx & 31;
        const int l   = t & 63;
        const int vc  = t >> 6;                // 0..3
        const int lq  = l >> 5, l31 = l & 31;
        const float* vsrc = V + (size_t)b * DT * NT;
        #pragma unroll
        for (int ci = 0; ci < 2; ++ci) {
            const int c = 2 * cg + ci;
            #pragma unroll
            for (int kk = 0; kk < 2; ++kk) {
                const float* p = vsrc + (size_t)(32 * vc + l31) * NT + 32 * c + 16 * kk + 8 * lq;
                const float4 x = *(const float4*)p;
                const float4 y = *(const float4*)(p + 4);
                bf16x8 f;
                f[0] = (__bf16)x.x; f[1] = (__bf16)x.y; f[2] = (__bf16)x.z; f[3] = (__bf16)x.w;
                f[4] = (__bf16)y.x; f[5] = (__bf16)y.y; f[6] = (__bf16)y.z; f[7] = (__bf16)y.w;
                *(bf16x8*)(Vf + ((size_t)((b * 64 + c) * 4 + vc) * 2 + kk) * 512 + l * 8) = f;
            }
        }
    }
}

// ============================================================================
// sig_attn5: zero LDS / zero barriers / coalesced fragment streams (round-3),
// NO GEMM1 duplication (512 blocks, wave owns m-column, all 4 v-tiles), and
// INTRA-WAVE SOFTWARE PIPELINE: chunk it+1's GEMM1 MFMAs are issued BEFORE
// chunk it's sigmoid VALU consumes s_cur, so MFMA executes under the ~400cy
// sigmoid/pack/exchange phase. Two named register sets (sA/sB, qfA/qfB),
// 2-phase unrolled loop -> all register indexing static (no scratch).
// Q fragment loads run depth-2 ahead so GEMM1(it+1) never waits on vmcnt.
//   mfma_f32_32x32x16_bf16 C/D: col=lane&31, row=(reg&3)+8*(reg>>2)+4*(lane>>5)
// Exchange (HW-proven in attn3/attn4): lane lq=0 holds S rows n={0-3,8-11,
// 16-19,24-27}, partner +32 holds n+4; 4x shfl_xor(32) + selects rebuild the
// two B-frags (n 0..15, n 16..31).
// ============================================================================
__global__ __launch_bounds__(256, 2)
void sig_attn5(const __bf16* __restrict__ Qf, const __bf16* __restrict__ Kf,
               const __bf16* __restrict__ Vf, float* __restrict__ wsp)
{
    const int t   = threadIdx.x;
    const int w   = t >> 6;       // wave 0..3 -> m-column
    const int l   = t & 63;
    const int lq  = l >> 5;
    const int l31 = l & 31;

    const int bid = blockIdx.x;
    const int b   = bid & 7;             // XCD-pinned batch
    const int mt  = (bid >> 3) & 15;
    const int ns  = bid >> 7;            // 0..3

    const int mrow = 32 * w + l31;       // local m within 128-tile

    // ---- K B-frags for this wave's m-column (8 coalesced 1KB loads)
    const __bf16* kfp = Kf + ((size_t)((b * 64 + 4 * mt + w) * 8)) * 512 + l * 8;
    bf16x8 kf[8];
    #pragma unroll
    for (int k = 0; k < 8; ++k) kf[k] = *(const bf16x8*)(kfp + (size_t)k * 512);

    const int c_base = ns * 16;
    const __bf16* qbase = Qf + ((size_t)(b * 64 + c_base) * 8) * 512 + l * 8;
    const __bf16* vbase = Vf + ((size_t)(b * 64 + c_base) * 8) * 512 + l * 8;

    f32x16 oacc[4];
    #pragma unroll
    for (int tv = 0; tv < 4; ++tv)
        #pragma unroll
        for (int r = 0; r < 16; ++r) oacc[tv][r] = 0.0f;

    // ---- prologue: Q frags for chunks 0 and 1; scores for chunk 0
    bf16x8 qfA[8], qfB[8];
    #pragma unroll
    for (int k = 0; k < 8; ++k) qfA[k] = *(const bf16x8*)(qbase + (size_t)k * 512);
    #pragma unroll
    for (int k = 0; k < 8; ++k) qfB[k] = *(const bf16x8*)(qbase + (size_t)(8 + k) * 512);

    f32x16 sA, sB;
    #pragma unroll
    for (int r = 0; r < 16; ++r) sA[r] = 0.0f;
    #pragma unroll
    for (int k = 0; k < 8; ++k)
        sA = __builtin_amdgcn_mfma_f32_32x32x16_bf16(qfA[k], kf[k], sA, 0, 0, 0);

    // body(it): SCUR = scores(it); QNXT = Q frags(it+1) [arrived];
    //           QCUR = dead -> reload with Q frags(it+2).
    auto body = [&](f32x16& SCUR, f32x16& SNXT,
                    bf16x8 (&QCUR)[8], bf16x8 (&QNXT)[8], int it_) {
        // -- Q depth-2 prefetch
        if (it_ < 14) {
            const __bf16* qn = qbase + (size_t)(it_ + 2) * 8 * 512;
            #pragma unroll
            for (int k = 0; k < 8; ++k) QCUR[k] = *(const bf16x8*)(qn + (size_t)k * 512);
        }
        // -- next chunk's GEMM1: issue MFMAs before consuming SCUR
        if (it_ < 15) {
            #pragma unroll
            for (int r = 0; r < 16; ++r) SNXT[r] = 0.0f;
            #pragma unroll
            for (int k = 0; k < 8; ++k)
                SNXT = __builtin_amdgcn_mfma_f32_32x32x16_bf16(QNXT[k], kf[k], SNXT, 0, 0, 0);
        }
        // -- V frags for this chunk (latency hides under sigmoid)
        const __bf16* vp_ = vbase + (size_t)it_ * 8 * 512;
        bf16x8 av[8];
        #pragma unroll
        for (int q = 0; q < 8; ++q) av[q] = *(const bf16x8*)(vp_ + (size_t)q * 512);

        // -- sigmoid(x/sqrt(128)) on SCUR (VALU; overlaps SNXT MFMAs + loads)
        float p[16];
        #pragma unroll
        for (int r = 0; r < 16; ++r) {
            const float e = __expf(SCUR[r] * -0.08838834764831845f);
            p[r] = __builtin_amdgcn_rcpf(1.0f + e);
        }

        // -- pack + half-wave exchange -> B-frags bs0 (n0..15), bs1 (n16..31)
        const uint32_t a0 = pk2(p[0],  p[1]),  b0 = pk2(p[2],  p[3]);
        const uint32_t c0 = pk2(p[4],  p[5]),  d0 = pk2(p[6],  p[7]);
        const uint32_t a1 = pk2(p[8],  p[9]),  b1 = pk2(p[10], p[11]);
        const uint32_t c1 = pk2(p[12], p[13]), d1 = pk2(p[14], p[15]);

        const uint32_t y0 = __shfl_xor(lq ? a0 : c0, 32);
        const uint32_t y1 = __shfl_xor(lq ? b0 : d0, 32);
        const uint32_t y2 = __shfl_xor(lq ? a1 : c1, 32);
        const uint32_t y3 = __shfl_xor(lq ? b1 : d1, 32);

        u32x4 f0, f1;
        f0[0] = lq ? y0 : a0;  f0[1] = lq ? y1 : b0;
        f0[2] = lq ? c0 : y0;  f0[3] = lq ? d0 : y1;
        f1[0] = lq ? y2 : a1;  f1[1] = lq ? y3 : b1;
        f1[2] = lq ? c1 : y2;  f1[3] = lq ? d1 : y3;
        const bf16x8 bs0 = __builtin_bit_cast(bf16x8, f0);
        const bf16x8 bs1 = __builtin_bit_cast(bf16x8, f1);

        // -- GEMM2: all 4 v-tiles (no duplication)
        #pragma unroll
        for (int tv = 0; tv < 4; ++tv) {
            oacc[tv] = __builtin_amdgcn_mfma_f32_32x32x16_bf16(av[2 * tv],     bs0, oacc[tv], 0, 0, 0);
            oacc[tv] = __builtin_amdgcn_mfma_f32_32x32x16_bf16(av[2 * tv + 1], bs1, oacc[tv], 0, 0, 0);
        }
    };

    #pragma unroll 1
    for (int i2 = 0; i2 < 8; ++i2) {
        body(sA, sB, qfA, qfB, 2 * i2);
        body(sB, sA, qfB, qfA, 2 * i2 + 1);
    }

    // ---- epilogue: per-block partial [v 128][m 128] (reduce4 layout)
    float* wsb = wsp + (size_t)bid * 16384;
    #pragma unroll
    for (int tv = 0; tv < 4; ++tv) {
        #pragma unroll
        for (int r = 0; r < 16; ++r) {
            const int v = 32 * tv + (r & 3) + 8 * (r >> 2) + 4 * lq;
            wsb[v * 128 + mrow] = oacc[tv][r];
        }
    }
}

// out[o] = sum over 4 n-splits of ws partials; float4 per thread, fully coalesced
__global__ __launch_bounds__(256)
void reduce4(const float4* __restrict__ ws, float4* __restrict__ out)
{
    const int i = blockIdx.x * 256 + threadIdx.x;
    const int o = i * 4;
    const int m_glob = o & 2047;
    const int vb     = o >> 11;
    const int v      = vb & 127;
    const int bb     = vb >> 7;
    const int mt     = m_glob >> 7;
    const int m      = m_glob & 127;
    const size_t base = ((size_t)(bb + 8 * mt) * 16384 + (size_t)v * 128 + m) >> 2;
    const size_t strd = 524288;
    float4 a = ws[base];
    float4 c = ws[base + strd];
    float4 d = ws[base + 2 * strd];
    float4 e = ws[base + 3 * strd];
    float4 r;
    r.x = a.x + c.x + d.x + e.x;
    r.y = a.y + c.y + d.y + e.y;
    r.z = a.z + c.z + d.z + e.z;
    r.w = a.w + c.w + d.w + e.w;
    out[i] = r;
}

// ============================================================================
// v1 kernel kept verbatim as fallback for small-ws harnesses
// ============================================================================
template <int WSMODE>
__global__ __launch_bounds__(512, 4)
void sig_attn(const float* __restrict__ Q, const float* __restrict__ K,
              const float* __restrict__ V, float* __restrict__ outp)
{
    __shared__ __align__(16) __bf16 Qs[64 * 128];
    __shared__ __align__(16) __bf16 Ss[128 * 64];
    __shared__ __align__(16) __bf16 Vs[2][128 * 64];

    const int t   = threadIdx.x;
    const int w   = t >> 6;
    const int l   = t & 63;
    const int lq  = l >> 5;
    const int l31 = l & 31;
    const int wm  = w & 3;
    const int wn  = w >> 2;

    const int bid    = blockIdx.x;
    const int b      = bid & 7;
    const int mt     = (bid >> 3) & 15;
    const int ns     = bid >> 7;
    const int m_blk  = mt * 128;
    const int n_base = ns * 512;

    const float* Qb = Q + (size_t)b * DT * NT;
    const float* Kb = K + (size_t)b * DT * NT;
    const float* Vb = V + (size_t)b * DT * NT;

    const int mrow = 32 * wm + l31;

    bf16x8 kf[8];
    #pragma unroll
    for (int half = 0; half < 2; ++half) {
        float tmp[4][8];
        #pragma unroll
        for (int k2 = 0; k2 < 4; ++k2)
            #pragma unroll
            for (int j = 0; j < 8; ++j)
                tmp[k2][j] = Kb[(size_t)((half * 4 + k2) * 16 + lq * 8 + j) * NT + m_blk + mrow];
        #pragma unroll
        for (int k2 = 0; k2 < 4; ++k2) {
            bf16x8 f;
            #pragma unroll
            for (int j = 0; j < 8; ++j) f[j] = (__bf16)tmp[k2][j];
            kf[half * 4 + k2] = f;
        }
    }

    f32x16 oacc[2];
    #pragma unroll
    for (int tv = 0; tv < 2; ++tv)
        #pragma unroll
        for (int r = 0; r < 16; ++r)
            oacc[tv][r] = 0.0f;

    float qp[16];
    #pragma unroll
    for (int r = 0; r < 2; ++r)
        #pragma unroll
        for (int j = 0; j < 8; ++j)
            qp[r * 8 + j] = Qb[(size_t)(64 * r + 8 * w + j) * NT + n_base + l];
    float4 vp[4];
    #pragma unroll
    for (int p = 0; p < 4; ++p)
        vp[p] = *(const float4*)(Vb + (size_t)(p * 32 + (t >> 4)) * NT + n_base + 4 * (t & 15));

    for (int it = 0; it < 8; ++it) {
        __bf16* Vbuf = Vs[it & 1];

        #pragma unroll
        for (int r = 0; r < 2; ++r) {
            bf16x8 pk;
            #pragma unroll
            for (int j = 0; j < 8; ++j) pk[j] = (__bf16)qp[r * 8 + j];
            *(bf16x8*)&Qs[l * 128 + ((8 * r + w) ^ (l & 15)) * 8] = pk;
        }
        #pragma unroll
        for (int p = 0; p < 4; ++p) {
            const int v  = p * 32 + (t >> 4);
            const int ng = t & 15;
            bf16x4 pk;
            pk[0] = (__bf16)vp[p].x;
            pk[1] = (__bf16)vp[p].y;
            pk[2] = (__bf16)vp[p].z;
            pk[3] = (__bf16)vp[p].w;
            *(bf16x4*)&Vbuf[v * 64 + ((ng >> 1) ^ (v & 7)) * 8 + 4 * (ng & 1)] = pk;
        }
        __syncthreads();

        const int n0n = n_base + ((it + 1) & 7) * 64;
        #pragma unroll
        for (int r = 0; r < 2; ++r)
            #pragma unroll
            for (int j = 0; j < 8; ++j)
                qp[r * 8 + j] = Qb[(size_t)(64 * r + 8 * w + j) * NT + n0n + l];
        #pragma unroll
        for (int p = 0; p < 4; ++p)
            vp[p] = *(const float4*)(Vb + (size_t)(p * 32 + (t >> 4)) * NT + n0n + 4 * (t & 15));

        f32x16 sacc;
        #pragma unroll
        for (int r = 0; r < 16; ++r) sacc[r] = 0.0f;
        const int nrow = 32 * wn + l31;
        #pragma unroll
        for (int k = 0; k < 8; ++k) {
            const bf16x8 af =
                *(const bf16x8*)&Qs[nrow * 128 + ((2 * k + lq) ^ (nrow & 15)) * 8];
            sacc = __builtin_amdgcn_mfma_f32_32x32x16_bf16(af, kf[k], sacc, 0, 0, 0);
        }

        #pragma unroll
        for (int g = 0; g < 4; ++g) {
            bf16x4 pk;
            #pragma unroll
            for (int rr = 0; rr < 4; ++rr) {
                const float x = sacc[4 * g + rr];
                const float e = __expf(x * -0.08838834764831845f);
                pk[rr] = (__bf16)__builtin_amdgcn_rcpf(1.0f + e);
            }
            *(bf16x4*)&Ss[mrow * 64 + ((4 * wn + g) ^ (mrow & 7)) * 8 + 4 * lq] = pk;
        }
        __syncthreads();

        #pragma unroll
        for (int k = 0; k < 4; ++k) {
            const int sw = 2 * k + lq;
            const bf16x8 av0 =
                *(const bf16x8*)&Vbuf[(64 * wn + l31) * 64 + (sw ^ (l31 & 7)) * 8];
            const bf16x8 av1 =
                *(const bf16x8*)&Vbuf[(64 * wn + 32 + l31) * 64 + (sw ^ (l31 & 7)) * 8];
            const bf16x8 bs =
                *(const bf16x8*)&Ss[mrow * 64 + (sw ^ (mrow & 7)) * 8];
            oacc[0] = __builtin_amdgcn_mfma_f32_32x32x16_bf16(av0, bs, oacc[0], 0, 0, 0);
            oacc[1] = __builtin_amdgcn_mfma_f32_32x32x16_bf16(av1, bs, oacc[1], 0, 0, 0);
        }
    }

    if (WSMODE == 0) {
        float* wsb = outp + (size_t)bid * 16384;
        #pragma unroll
        for (int tv = 0; tv < 2; ++tv) {
            #pragma unroll
            for (int r = 0; r < 16; ++r) {
                const int v = 64 * wn + 32 * tv + (r & 3) + 8 * (r >> 2) + 4 * lq;
                wsb[v * 128 + mrow] = oacc[tv][r];
            }
        }
    } else {
        float* Ob = outp + (size_t)b * DT * NT;
        #pragma unroll
        for (int tv = 0; tv < 2; ++tv) {
            #pragma unroll
            for (int r = 0; r < 16; ++r) {
                const int v = 64 * wn + 32 * tv + (r & 3) + 8 * (r >> 2) + 4 * lq;
                atomicAdd(&Ob[(size_t)v * NT + m_blk + mrow], oacc[tv][r]);
            }
        }
    }
}

extern "C" void kernel_launch(void* const* d_in, const int* in_sizes, int n_in,
                              void* d_out, int out_size, void* d_ws, size_t ws_size,
                              hipStream_t stream) {
    (void)in_sizes; (void)n_in;
    const float* Q = (const float*)d_in[0];
    const float* K = (const float*)d_in[1];
    const float* V = (const float*)d_in[2];
    const size_t PART  = (size_t)512 * 16384 * 4;          // 33.5 MB fp32 partials
    const size_t FRAGB = (size_t)2097152 * 2;              // 4 MB per operand buffer
    if (ws_size >= PART + 3 * FRAGB) {                     // 45.6 MB (<= proven 46.1)
        __bf16* Qf = (__bf16*)((char*)d_ws + PART);
        __bf16* Kf = Qf + 2097152;
        __bf16* Vf = Kf + 2097152;
        prep2<<<dim3(768), dim3(256), 0, stream>>>(Q, K, V, Qf, Kf, Vf);
        sig_attn5<<<dim3(512), dim3(256), 0, stream>>>(Qf, Kf, Vf, (float*)d_ws);
        reduce4<<<dim3(2048), dim3(256), 0, stream>>>((const float4*)d_ws, (float4*)d_out);
    } else if (ws_size >= PART) {
        sig_attn<0><<<dim3(512), dim3(512), 0, stream>>>(Q, K, V, (float*)d_ws);
        reduce4<<<dim3(2048), dim3(256), 0, stream>>>((const float4*)d_ws, (float4*)d_out);
    } else {
        hipMemsetAsync(d_out, 0, (size_t)out_size * sizeof(float), stream);
        sig_attn<1><<<dim3(512), dim3(512), 0, stream>>>(Q, K, V, (float*)d_out);
    }
}

// Round 5
// 105.792 us; speedup vs baseline: 1.3762x; 1.0486x over previous
//
#include <hip/hip_runtime.h>
#include <stdint.h>

#define NT 2048
#define DT 128

typedef __bf16 bf16x8 __attribute__((ext_vector_type(8)));
typedef __bf16 bf16x4 __attribute__((ext_vector_type(4)));
typedef float  f32x16 __attribute__((ext_vector_type(16)));
typedef uint32_t u32x4 __attribute__((ext_vector_type(4)));

static __device__ __forceinline__ uint32_t pk2(float lo, float hi) {
    union { __bf16 h[2]; uint32_t u; } un;
    un.h[0] = (__bf16)lo; un.h[1] = (__bf16)hi;
    return un.u;
}

// v_permlane32_swap_b32: after execution x' = {x.lo32lanes, y.lo32lanes},
// y' = {x.hi32lanes, y.hi32lanes} (each lane i<32 of x' keeps x[i]; lane i>=32
// of x' gets y[i-32]; lane i<32 of y' gets x[i+32]; lane i>=32 of y' keeps y[i]).
// s_nop guards: 1 wait-state for VALU->permlane src, 2 for permlane->MFMA src.
static __device__ __forceinline__ void lane32_swap(uint32_t& x, uint32_t& y) {
    asm("s_nop 0\n\tv_permlane32_swap_b32 %0, %1\n\ts_nop 1"
        : "+v"(x), "+v"(y));
}

// ============================================================================
// prep2: convert Q,K,V fp32 into MFMA-FRAGMENT-ORDER bf16 buffers so every
// fragment load in the main kernel is one coalesced 1KB wave-load.
//   Qf[b][c][k][l][j] = Q[b][d=16k+8*(l>>5)+j][n=32c+(l&31)]     (4 MB)
//   Kf[b][mc][k][l][j] = K[b][d=16k+8*(l>>5)+j][m=32mc+(l&31)]   (4 MB)
//   Vf[b][c][vc][kk][l][j] = V[b][v=32vc+(l&31)][n=32c+16kk+8*(l>>5)+j] (4 MB)
// blocks 0..511: Q/K (LDS transpose of a [128d][64n] tile); 512..767: V.
// ============================================================================
__global__ __launch_bounds__(256)
void prep2(const float* __restrict__ Q, const float* __restrict__ K,
           const float* __restrict__ V,
           __bf16* __restrict__ Qf, __bf16* __restrict__ Kf, __bf16* __restrict__ Vf)
{
    const int bid = blockIdx.x;
    const int t   = threadIdx.x;
    if (bid < 512) {
        __shared__ float ls[128][65];
        const int which = bid >> 8;            // 0=Q, 1=K
        const float* src = which ? K : Q;
        __bf16*      dst = which ? Kf : Qf;
        const int idx = bid & 255;
        const int b   = idx >> 5;              // 0..7
        const int ct  = idx & 31;              // 64-wide n/m tile
        const int n0  = ct * 64;
        const float* sb = src + (size_t)b * DT * NT;
        #pragma unroll
        for (int rr = 0; rr < 8; ++rr) {
            const int d = (t >> 4) + 16 * rr;
            const float4 v4 = *(const float4*)(sb + (size_t)d * NT + n0 + 4 * (t & 15));
            ls[d][4 * (t & 15) + 0] = v4.x;
            ls[d][4 * (t & 15) + 1] = v4.y;
            ls[d][4 * (t & 15) + 2] = v4.z;
            ls[d][4 * (t & 15) + 3] = v4.w;
        }
        __syncthreads();
        const int l  = t & 63;
        const int kq = t >> 6;                 // 0..3
        const int lq = l >> 5, l31 = l & 31;
        #pragma unroll
        for (int c = 0; c < 2; ++c) {
            #pragma unroll
            for (int kh = 0; kh < 2; ++kh) {
                const int k = kq + 4 * kh;
                bf16x8 f;
                #pragma unroll
                for (int j = 0; j < 8; ++j)
                    f[j] = (__bf16)ls[16 * k + 8 * lq + j][32 * c + l31];
                *(bf16x8*)(dst + ((size_t)((b * 64 + 2 * ct + c) * 8 + k)) * 512 + l * 8) = f;
            }
        }
    } else {
        const int idx = bid - 512;             // 0..255
        const int b   = idx >> 5;
        const int cg  = idx & 31;
        const int l   = t & 63;
        const int vc  = t >> 6;                // 0..3
        const int lq  = l >> 5, l31 = l & 31;
        const float* vsrc = V + (size_t)b * DT * NT;
        #pragma unroll
        for (int ci = 0; ci < 2; ++ci) {
            const int c = 2 * cg + ci;
            #pragma unroll
            for (int kk = 0; kk < 2; ++kk) {
                const float* p = vsrc + (size_t)(32 * vc + l31) * NT + 32 * c + 16 * kk + 8 * lq;
                const float4 x = *(const float4*)p;
                const float4 y = *(const float4*)(p + 4);
                bf16x8 f;
                f[0] = (__bf16)x.x; f[1] = (__bf16)x.y; f[2] = (__bf16)x.z; f[3] = (__bf16)x.w;
                f[4] = (__bf16)y.x; f[5] = (__bf16)y.y; f[6] = (__bf16)y.z; f[7] = (__bf16)y.w;
                *(bf16x8*)(Vf + ((size_t)((b * 64 + c) * 4 + vc) * 2 + kk) * 512 + l * 8) = f;
            }
        }
    }
}

// ============================================================================
// sig_attn6: attn5 skeleton (zero LDS / zero barriers / coalesced fragment
// streams / intra-wave SW pipeline with named register sets) with two
// critical-path fixes:
//  (1) C->B exchange via 4x v_permlane32_swap_b32 (VALU, ~2cy) instead of
//      4x ds_bpermute shfl (+12 cndmask, lgkm waits) — removes the LDS-pipe
//      latency from the sigmoid->GEMM2 chain.
//      swap(a0,c0) -> {w0,w2}; swap(b0,d0) -> {w1,w3} of bs0 (all lanes);
//      swap(a1,c1)/swap(b1,d1) -> bs1. Mapping verified against the
//      HW-proven shfl version (attn3/4/5).
//  (2) V fragments prefetched depth-1: loaded at END of body it (right after
//      GEMM2 releases av), consumed next body — full body of latency slack.
//   mfma_f32_32x32x16_bf16 C/D: col=lane&31, row=(reg&3)+8*(reg>>2)+4*(lane>>5)
// ============================================================================
__global__ __launch_bounds__(256, 2)
void sig_attn6(const __bf16* __restrict__ Qf, const __bf16* __restrict__ Kf,
               const __bf16* __restrict__ Vf, float* __restrict__ wsp)
{
    const int t   = threadIdx.x;
    const int w   = t >> 6;       // wave 0..3 -> m-column
    const int l   = t & 63;
    const int lq  = l >> 5;
    const int l31 = l & 31;

    const int bid = blockIdx.x;
    const int b   = bid & 7;             // XCD-pinned batch
    const int mt  = (bid >> 3) & 15;
    const int ns  = bid >> 7;            // 0..3

    const int mrow = 32 * w + l31;       // local m within 128-tile

    // ---- K B-frags for this wave's m-column (8 coalesced 1KB loads)
    const __bf16* kfp = Kf + ((size_t)((b * 64 + 4 * mt + w) * 8)) * 512 + l * 8;
    bf16x8 kf[8];
    #pragma unroll
    for (int k = 0; k < 8; ++k) kf[k] = *(const bf16x8*)(kfp + (size_t)k * 512);

    const int c_base = ns * 16;
    const __bf16* qbase = Qf + ((size_t)(b * 64 + c_base) * 8) * 512 + l * 8;
    const __bf16* vbase = Vf + ((size_t)(b * 64 + c_base) * 8) * 512 + l * 8;

    f32x16 oacc[4];
    #pragma unroll
    for (int tv = 0; tv < 4; ++tv)
        #pragma unroll
        for (int r = 0; r < 16; ++r) oacc[tv][r] = 0.0f;

    // ---- prologue: Q frags chunks 0,1; V frags chunk 0; scores chunk 0
    bf16x8 qfA[8], qfB[8], av[8];
    #pragma unroll
    for (int k = 0; k < 8; ++k) qfA[k] = *(const bf16x8*)(qbase + (size_t)k * 512);
    #pragma unroll
    for (int k = 0; k < 8; ++k) qfB[k] = *(const bf16x8*)(qbase + (size_t)(8 + k) * 512);
    #pragma unroll
    for (int q = 0; q < 8; ++q) av[q] = *(const bf16x8*)(vbase + (size_t)q * 512);

    f32x16 sA, sB;
    #pragma unroll
    for (int r = 0; r < 16; ++r) sA[r] = 0.0f;
    #pragma unroll
    for (int k = 0; k < 8; ++k)
        sA = __builtin_amdgcn_mfma_f32_32x32x16_bf16(qfA[k], kf[k], sA, 0, 0, 0);

    // body(it): SCUR = scores(it); QNXT = Q frags(it+1) [loaded 2 bodies ago];
    //           av = V frags(it) [loaded last body]; QCUR reloads it+2;
    //           av reloads it+1 at the end (after GEMM2 releases it).
    auto body = [&](f32x16& SCUR, f32x16& SNXT,
                    bf16x8 (&QCUR)[8], bf16x8 (&QNXT)[8], int it_) {
        // -- Q depth-2 prefetch
        if (it_ < 14) {
            const __bf16* qn = qbase + (size_t)(it_ + 2) * 8 * 512;
            #pragma unroll
            for (int k = 0; k < 8; ++k) QCUR[k] = *(const bf16x8*)(qn + (size_t)k * 512);
        }
        // -- next chunk's GEMM1: MFMAs issued before SCUR is consumed
        if (it_ < 15) {
            #pragma unroll
            for (int r = 0; r < 16; ++r) SNXT[r] = 0.0f;
            #pragma unroll
            for (int k = 0; k < 8; ++k)
                SNXT = __builtin_amdgcn_mfma_f32_32x32x16_bf16(QNXT[k], kf[k], SNXT, 0, 0, 0);
        }

        // -- sigmoid(x/sqrt(128)) on SCUR (VALU/TRANS; overlaps SNXT MFMAs)
        float p[16];
        #pragma unroll
        for (int r = 0; r < 16; ++r) {
            const float e = __expf(SCUR[r] * -0.08838834764831845f);
            p[r] = __builtin_amdgcn_rcpf(1.0f + e);
        }

        // -- pack to bf16 pairs + permlane32 exchange -> B-frags
        uint32_t e0 = pk2(p[0],  p[1]),  e1 = pk2(p[2],  p[3]);
        uint32_t e2 = pk2(p[4],  p[5]),  e3 = pk2(p[6],  p[7]);
        uint32_t g0 = pk2(p[8],  p[9]),  g1 = pk2(p[10], p[11]);
        uint32_t g2 = pk2(p[12], p[13]), g3 = pk2(p[14], p[15]);

        lane32_swap(e0, e2);   // e0 = bs0.w0, e2 = bs0.w2
        lane32_swap(e1, e3);   // e1 = bs0.w1, e3 = bs0.w3
        lane32_swap(g0, g2);   // g0 = bs1.w0, g2 = bs1.w2
        lane32_swap(g1, g3);   // g1 = bs1.w1, g3 = bs1.w3

        u32x4 f0, f1;
        f0[0] = e0; f0[1] = e1; f0[2] = e2; f0[3] = e3;
        f1[0] = g0; f1[1] = g1; f1[2] = g2; f1[3] = g3;
        const bf16x8 bs0 = __builtin_bit_cast(bf16x8, f0);
        const bf16x8 bs1 = __builtin_bit_cast(bf16x8, f1);

        // -- GEMM2: all 4 v-tiles; av was loaded a full body ago
        #pragma unroll
        for (int tv = 0; tv < 4; ++tv) {
            oacc[tv] = __builtin_amdgcn_mfma_f32_32x32x16_bf16(av[2 * tv],     bs0, oacc[tv], 0, 0, 0);
            oacc[tv] = __builtin_amdgcn_mfma_f32_32x32x16_bf16(av[2 * tv + 1], bs1, oacc[tv], 0, 0, 0);
        }

        // -- V depth-1 prefetch into the just-released av registers
        if (it_ < 15) {
            const __bf16* vn = vbase + (size_t)(it_ + 1) * 8 * 512;
            #pragma unroll
            for (int q = 0; q < 8; ++q) av[q] = *(const bf16x8*)(vn + (size_t)q * 512);
        }
    };

    #pragma unroll 1
    for (int i2 = 0; i2 < 8; ++i2) {
        body(sA, sB, qfA, qfB, 2 * i2);
        body(sB, sA, qfB, qfA, 2 * i2 + 1);
    }

    // ---- epilogue: per-block partial [v 128][m 128] (reduce4 layout)
    float* wsb = wsp + (size_t)bid * 16384;
    #pragma unroll
    for (int tv = 0; tv < 4; ++tv) {
        #pragma unroll
        for (int r = 0; r < 16; ++r) {
            const int v = 32 * tv + (r & 3) + 8 * (r >> 2) + 4 * lq;
            wsb[v * 128 + mrow] = oacc[tv][r];
        }
    }
}

// out[o] = sum over 4 n-splits of ws partials; float4 per thread, fully coalesced
__global__ __launch_bounds__(256)
void reduce4(const float4* __restrict__ ws, float4* __restrict__ out)
{
    const int i = blockIdx.x * 256 + threadIdx.x;
    const int o = i * 4;
    const int m_glob = o & 2047;
    const int vb     = o >> 11;
    const int v      = vb & 127;
    const int bb     = vb >> 7;
    const int mt     = m_glob >> 7;
    const int m      = m_glob & 127;
    const size_t base = ((size_t)(bb + 8 * mt) * 16384 + (size_t)v * 128 + m) >> 2;
    const size_t strd = 524288;
    float4 a = ws[base];
    float4 c = ws[base + strd];
    float4 d = ws[base + 2 * strd];
    float4 e = ws[base + 3 * strd];
    float4 r;
    r.x = a.x + c.x + d.x + e.x;
    r.y = a.y + c.y + d.y + e.y;
    r.z = a.z + c.z + d.z + e.z;
    r.w = a.w + c.w + d.w + e.w;
    out[i] = r;
}

// ============================================================================
// v1 kernel kept verbatim as fallback for small-ws harnesses
// ============================================================================
template <int WSMODE>
__global__ __launch_bounds__(512, 4)
void sig_attn(const float* __restrict__ Q, const float* __restrict__ K,
              const float* __restrict__ V, float* __restrict__ outp)
{
    __shared__ __align__(16) __bf16 Qs[64 * 128];
    __shared__ __align__(16) __bf16 Ss[128 * 64];
    __shared__ __align__(16) __bf16 Vs[2][128 * 64];

    const int t   = threadIdx.x;
    const int w   = t >> 6;
    const int l   = t & 63;
    const int lq  = l >> 5;
    const int l31 = l & 31;
    const int wm  = w & 3;
    const int wn  = w >> 2;

    const int bid    = blockIdx.x;
    const int b      = bid & 7;
    const int mt     = (bid >> 3) & 15;
    const int ns     = bid >> 7;
    const int m_blk  = mt * 128;
    const int n_base = ns * 512;

    const float* Qb = Q + (size_t)b * DT * NT;
    const float* Kb = K + (size_t)b * DT * NT;
    const float* Vb = V + (size_t)b * DT * NT;

    const int mrow = 32 * wm + l31;

    bf16x8 kf[8];
    #pragma unroll
    for (int half = 0; half < 2; ++half) {
        float tmp[4][8];
        #pragma unroll
        for (int k2 = 0; k2 < 4; ++k2)
            #pragma unroll
            for (int j = 0; j < 8; ++j)
                tmp[k2][j] = Kb[(size_t)((half * 4 + k2) * 16 + lq * 8 + j) * NT + m_blk + mrow];
        #pragma unroll
        for (int k2 = 0; k2 < 4; ++k2) {
            bf16x8 f;
            #pragma unroll
            for (int j = 0; j < 8; ++j) f[j] = (__bf16)tmp[k2][j];
            kf[half * 4 + k2] = f;
        }
    }

    f32x16 oacc[2];
    #pragma unroll
    for (int tv = 0; tv < 2; ++tv)
        #pragma unroll
        for (int r = 0; r < 16; ++r)
            oacc[tv][r] = 0.0f;

    float qp[16];
    #pragma unroll
    for (int r = 0; r < 2; ++r)
        #pragma unroll
        for (int j = 0; j < 8; ++j)
            qp[r * 8 + j] = Qb[(size_t)(64 * r + 8 * w + j) * NT + n_base + l];
    float4 vp[4];
    #pragma unroll
    for (int p = 0; p < 4; ++p)
        vp[p] = *(const float4*)(Vb + (size_t)(p * 32 + (t >> 4)) * NT + n_base + 4 * (t & 15));

    for (int it = 0; it < 8; ++it) {
        __bf16* Vbuf = Vs[it & 1];

        #pragma unroll
        for (int r = 0; r < 2; ++r) {
            bf16x8 pk;
            #pragma unroll
            for (int j = 0; j < 8; ++j) pk[j] = (__bf16)qp[r * 8 + j];
            *(bf16x8*)&Qs[l * 128 + ((8 * r + w) ^ (l & 15)) * 8] = pk;
        }
        #pragma unroll
        for (int p = 0; p < 4; ++p) {
            const int v  = p * 32 + (t >> 4);
            const int ng = t & 15;
            bf16x4 pk;
            pk[0] = (__bf16)vp[p].x;
            pk[1] = (__bf16)vp[p].y;
            pk[2] = (__bf16)vp[p].z;
            pk[3] = (__bf16)vp[p].w;
            *(bf16x4*)&Vbuf[v * 64 + ((ng >> 1) ^ (v & 7)) * 8 + 4 * (ng & 1)] = pk;
        }
        __syncthreads();

        const int n0n = n_base + ((it + 1) & 7) * 64;
        #pragma unroll
        for (int r = 0; r < 2; ++r)
            #pragma unroll
            for (int j = 0; j < 8; ++j)
                qp[r * 8 + j] = Qb[(size_t)(64 * r + 8 * w + j) * NT + n0n + l];
        #pragma unroll
        for (int p = 0; p < 4; ++p)
            vp[p] = *(const float4*)(Vb + (size_t)(p * 32 + (t >> 4)) * NT + n0n + 4 * (t & 15));

        f32x16 sacc;
        #pragma unroll
        for (int r = 0; r < 16; ++r) sacc[r] = 0.0f;
        const int nrow = 32 * wn + l31;
        #pragma unroll
        for (int k = 0; k < 8; ++k) {
            const bf16x8 af =
                *(const bf16x8*)&Qs[nrow * 128 + ((2 * k + lq) ^ (nrow & 15)) * 8];
            sacc = __builtin_amdgcn_mfma_f32_32x32x16_bf16(af, kf[k], sacc, 0, 0, 0);
        }

        #pragma unroll
        for (int g = 0; g < 4; ++g) {
            bf16x4 pk;
            #pragma unroll
            for (int rr = 0; rr < 4; ++rr) {
                const float x = sacc[4 * g + rr];
                const float e = __expf(x * -0.08838834764831845f);
                pk[rr] = (__bf16)__builtin_amdgcn_rcpf(1.0f + e);
            }
            *(bf16x4*)&Ss[mrow * 64 + ((4 * wn + g) ^ (mrow & 7)) * 8 + 4 * lq] = pk;
        }
        __syncthreads();

        #pragma unroll
        for (int k = 0; k < 4; ++k) {
            const int sw = 2 * k + lq;
            const bf16x8 av0 =
                *(const bf16x8*)&Vbuf[(64 * wn + l31) * 64 + (sw ^ (l31 & 7)) * 8];
            const bf16x8 av1 =
                *(const bf16x8*)&Vbuf[(64 * wn + 32 + l31) * 64 + (sw ^ (l31 & 7)) * 8];
            const bf16x8 bs =
                *(const bf16x8*)&Ss[mrow * 64 + (sw ^ (mrow & 7)) * 8];
            oacc[0] = __builtin_amdgcn_mfma_f32_32x32x16_bf16(av0, bs, oacc[0], 0, 0, 0);
            oacc[1] = __builtin_amdgcn_mfma_f32_32x32x16_bf16(av1, bs, oacc[1], 0, 0, 0);
        }
    }

    if (WSMODE == 0) {
        float* wsb = outp + (size_t)bid * 16384;
        #pragma unroll
        for (int tv = 0; tv < 2; ++tv) {
            #pragma unroll
            for (int r = 0; r < 16; ++r) {
                const int v = 64 * wn + 32 * tv + (r & 3) + 8 * (r >> 2) + 4 * lq;
                wsb[v * 128 + mrow] = oacc[tv][r];
            }
        }
    } else {
        float* Ob = outp + (size_t)b * DT * NT;
        #pragma unroll
        for (int tv = 0; tv < 2; ++tv) {
            #pragma unroll
            for (int r = 0; r < 16; ++r) {
                const int v = 64 * wn + 32 * tv + (r & 3) + 8 * (r >> 2) + 4 * lq;
                atomicAdd(&Ob[(size_t)v * NT + m_blk + mrow], oacc[tv][r]);
            }
        }
    }
}

extern "C" void kernel_launch(void* const* d_in, const int* in_sizes, int n_in,
                              void* d_out, int out_size, void* d_ws, size_t ws_size,
                              hipStream_t stream) {
    (void)in_sizes; (void)n_in;
    const float* Q = (const float*)d_in[0];
    const float* K = (const float*)d_in[1];
    const float* V = (const float*)d_in[2];
    const size_t PART  = (size_t)512 * 16384 * 4;          // 33.5 MB fp32 partials
    const size_t FRAGB = (size_t)2097152 * 2;              // 4 MB per operand buffer
    if (ws_size >= PART + 3 * FRAGB) {                     // 45.6 MB (ws is 256 MiB)
        __bf16* Qf = (__bf16*)((char*)d_ws + PART);
        __bf16* Kf = Qf + 2097152;
        __bf16* Vf = Kf + 2097152;
        prep2<<<dim3(768), dim3(256), 0, stream>>>(Q, K, V, Qf, Kf, Vf);
        sig_attn6<<<dim3(512), dim3(256), 0, stream>>>(Qf, Kf, Vf, (float*)d_ws);
        reduce4<<<dim3(2048), dim3(256), 0, stream>>>((const float4*)d_ws, (float4*)d_out);
    } else if (ws_size >= PART) {
        sig_attn<0><<<dim3(512), dim3(512), 0, stream>>>(Q, K, V, (float*)d_ws);
        reduce4<<<dim3(2048), dim3(256), 0, stream>>>((const float4*)d_ws, (float4*)d_out);
    } else {
        hipMemsetAsync(d_out, 0, (size_t)out_size * sizeof(float), stream);
        sig_attn<1><<<dim3(512), dim3(512), 0, stream>>>(Q, K, V, (float*)d_out);
    }
}